// Round 5
// baseline (7252.076 us; speedup 1.0000x reference)
//
#include <hip/hip_runtime.h>
#include <cstdint>

typedef unsigned short u16;
typedef __attribute__((ext_vector_type(8))) short short8;     // 8 x bf16 (4 VGPRs)
typedef __attribute__((ext_vector_type(4))) short short4v;    // 4 x bf16 (2 VGPRs)
typedef __attribute__((ext_vector_type(4))) float f32x4;
typedef __attribute__((ext_vector_type(16))) float f32x16;

// B=64, T=512, H=512, D_IN=1024, L=2, DIRS=2
// xg matrix: M = T*B = 32768 rows (m = t*64 + b), N = 4096 cols (n = dir*2048 + gate*512 + j)

__device__ __forceinline__ u16 f2bf(float x){
  uint32_t u = __float_as_uint(x);
  u += 0x7fffu + ((u >> 16) & 1u);          // RNE
  return (u16)(u >> 16);
}
__device__ __forceinline__ float bf2f(u16 b){ return __uint_as_float(((uint32_t)b) << 16); }
__device__ __forceinline__ float sigm(float x){ return 1.f / (1.f + __expf(-x)); }
__device__ __forceinline__ float tanhx(float x){
  float xc = fminf(fmaxf(x, -30.f), 30.f);
  float e  = __expf(-2.f * xc);
  return (1.f - e) / (1.f + e);
}

// XCD-local data ops (write-once/read-once addresses ONLY -- L2-served).
__device__ __forceinline__ void st8_l2(u16* p, short4v v){
  asm volatile("global_store_dwordx2 %0, %1, off sc0" :: "v"(p), "v"(v) : "memory");
}
// agent-scope flag store (coherent point). Spin-polled addresses MUST use sc1:
// round-4 evidence: sc0-only flag store/poll deadlocks (stale line re-read forever).
__device__ __forceinline__ void st4_ag(int* p, int v){
  asm volatile("global_store_dword %0, %1, off sc1" :: "v"(p), "v"(v) : "memory");
}

// ---------------- fp32 -> bf16 convert ----------------
__global__ void k_cvt(const float* __restrict__ in, u16* __restrict__ out, int n4){
  int i = blockIdx.x * blockDim.x + threadIdx.x;
  if (i >= n4) return;
  float4 v = ((const float4*)in)[i];
  ushort4 o;
  o.x = f2bf(v.x); o.y = f2bf(v.y); o.z = f2bf(v.z); o.w = f2bf(v.w);
  ((ushort4*)out)[i] = o;
}

// ---------------- input GEMM: xg = A @ W^T + bias, bf16 in, bf16 out ----------------
template<int LAYER0>
__global__ __launch_bounds__(256) void k_gemm(
    const u16* __restrict__ A, const u16* __restrict__ W,
    const float* __restrict__ bih, const float* __restrict__ bhh,
    u16* __restrict__ xg)
{
  __shared__ u16 Al[128 * 64];
  __shared__ u16 Bl[128 * 64];
  const int tid  = threadIdx.x;
  const int bm   = blockIdx.x, bn = blockIdx.y;
  const int w    = tid >> 6, lane = tid & 63;
  const int wm   = (w >> 1) * 64;
  const int wn   = (w & 1) * 64;
  f32x4 acc[4][4] = {};

  for (int kt = 0; kt < 1024; kt += 64){
    __syncthreads();
    #pragma unroll
    for (int it = 0; it < 4; ++it){
      int idx = tid + it * 256;
      int row = idx >> 3, c = idx & 7;
      size_t aoff;
      int m = bm * 128 + row;
      if (LAYER0) aoff = ((size_t)(m & 63) * 512 + (m >> 6)) * 1024;
      else        aoff = (size_t)m * 1024;
      short8 va = *(const short8*)(A + aoff + kt + c * 8);
      *(short8*)(Al + row * 64 + ((c ^ (row & 7)) * 8)) = va;
      int n = bn * 128 + row;
      short8 vb = *(const short8*)(W + (size_t)n * 1024 + kt + c * 8);
      *(short8*)(Bl + row * 64 + ((c ^ (row & 7)) * 8)) = vb;
    }
    __syncthreads();
    const int kg = lane >> 4;
    #pragma unroll
    for (int kk = 0; kk < 2; ++kk){
      short8 a[4], b[4];
      #pragma unroll
      for (int i = 0; i < 4; ++i){
        int rA = wm + i * 16 + (lane & 15);
        int cA = kk * 4 + kg;
        a[i] = *(const short8*)(Al + rA * 64 + ((cA ^ (rA & 7)) * 8));
        int rB = wn + i * 16 + (lane & 15);
        b[i] = *(const short8*)(Bl + rB * 64 + ((cA ^ (rB & 7)) * 8));
      }
      #pragma unroll
      for (int i = 0; i < 4; ++i)
        #pragma unroll
        for (int j = 0; j < 4; ++j)
          acc[i][j] = __builtin_amdgcn_mfma_f32_16x16x32_bf16(a[i], b[j], acc[i][j], 0, 0, 0);
    }
  }
  #pragma unroll
  for (int i = 0; i < 4; ++i){
    #pragma unroll
    for (int j = 0; j < 4; ++j){
      int n_g = bn * 128 + wn + j * 16 + (lane & 15);
      float bias = bih[n_g] + bhh[n_g];
      #pragma unroll
      for (int q = 0; q < 4; ++q){
        int m_g = bm * 128 + wm + i * 16 + (lane >> 4) * 4 + q;
        xg[(size_t)m_g * 4096 + n_g] = f2bf(acc[i][j][q] + bias);
      }
    }
  }
}

// ---------------- persistent LSTM recurrence, XCD-local exchange ----------------
// Election (round-3 proven): first 32 WGs per XCD are workers; first XCD claims dir0,
// second dir1; others exit. One dir == one XCD => h exchange stays in XCD-local L2.
// Round-5: NO LDS staging of h -- each wave feeds MFMA A-frags straight from L2 via a
// 12-deep pipelined gather (manual counted vmcnt). Waves poll flags independently;
// only 2 __syncthreads per step (gates exchange + store drain).
template<int LAYER>
__global__ __launch_bounds__(256, 1) void k_rec(
    const u16* __restrict__ whh,   // (2, 2048, 512) bf16, this layer
    const u16* __restrict__ xg,    // (32768, 4096) bf16
    u16*  __restrict__ x1,         // (32768, 1024) bf16: layer0 output + layer0 h exchange
    u16*  __restrict__ hexch,      // [512 t][2 dir][64][512] bf16: layer1 h exchange
    float* __restrict__ dout,      // (64, 512, 1024) fp32 final output
    int*  __restrict__ ctrl,       // election block: cnt[8*16], dirmap@128..135, ndirs@136
    int*  __restrict__ flg)        // flags: [dir*64 + s], step counters
{
  const int tid = threadIdx.x;
  __shared__ int sh_rank, sh_dir;

  if (tid == 0){
    uint32_t xcd;
    asm volatile("s_getreg_b32 %0, hwreg(HW_REG_XCC_ID)" : "=s"(xcd));
    xcd &= 7;
    int rank = __hip_atomic_fetch_add(ctrl + xcd * 16, 1, __ATOMIC_RELAXED, __HIP_MEMORY_SCOPE_AGENT);
    int dm;
    if (rank == 0){
      int slot = __hip_atomic_fetch_add(ctrl + 136, 1, __ATOMIC_RELAXED, __HIP_MEMORY_SCOPE_AGENT);
      dm = slot + 1;
      __hip_atomic_store(ctrl + 128 + xcd, dm, __ATOMIC_RELEASE, __HIP_MEMORY_SCOPE_AGENT);
    } else {
      do {
        dm = __hip_atomic_load(ctrl + 128 + xcd, __ATOMIC_ACQUIRE, __HIP_MEMORY_SCOPE_AGENT);
      } while (dm == 0);
    }
    sh_rank = rank; sh_dir = dm - 1;
  }
  __syncthreads();
  const int s   = sh_rank;
  const int dir = sh_dir;
  if (s >= 32 || dir >= 2) return;     // not a worker

  const int w    = tid >> 6, lane = tid & 63;
  const int wm   = (w >> 1) * 32;      // batch-row offset of this wave
  const int wn   = (w & 1) * 32;       // col offset within WG's 64 cols

  __shared__ float gates_lds[4][64][16];   // 16 KB

  // W^T slice into registers: B-frag[kk]: B[k][n], n = wn+(lane&31)
  const u16* wd = whh + (size_t)dir * (2048 * 512);
  const int  nl = wn + (lane & 31);
  const int  g_of_n = nl >> 4, j_of_n = nl & 15;
  short8 bq[32];
  {
    const size_t rbase = (size_t)(g_of_n * 512 + s * 16 + j_of_n) * 512;
    const int ko = (lane >> 5) * 8;
    #pragma unroll
    for (int kk = 0; kk < 32; ++kk)
      bq[kk] = *(const short8*)(wd + rbase + kk * 16 + ko);
  }

  float cst[4] = {0.f, 0.f, 0.f, 0.f};
  const int tstep = dir ? -1 : 1;
  const int t0    = dir ? 511 : 0;
  int* const flgd = flg + dir * 64;

  // A-frag geometry: row m (batch), k-half per lane
  const int am  = wm + (lane & 31);
  const int cb8 = (lane >> 5) * 8;     // element offset of this lane's k-half

  // gate-math geometry: thread owns batch gm, cols gj..gj+3
  const int gm = tid >> 2;
  const int gj = 4 * (tid & 3);

  for (int it = 0; it < 512; ++it){
    const int t = t0 + tstep * it;

    // prefetch this step's xg gate values (plain cached loads; drain during poll)
    const size_t xb0 = ((size_t)t * 64 + gm) * 4096 + (size_t)dir * 2048 + s * 16 + gj;
    ushort4 xgv[4];
    #pragma unroll
    for (int g = 0; g < 4; ++g) xgv[g] = *(const ushort4*)(xg + xb0 + g * 512);

    float accv[16];
    #pragma unroll
    for (int r = 0; r < 16; ++r) accv[r] = 0.f;

    if (it > 0){
      const int tprev = t - tstep;
      // ---- every wave independently waits for all 32 producers (sc1 poll) ----
      {
        const int* fp = flgd + (lane & 31);
        while (true){
          int v;
          asm volatile("global_load_dword %0, %1, off sc1\n\ts_waitcnt vmcnt(0)"
                       : "=v"(v) : "v"(fp) : "memory");
          if (__all(v >= it)) break;
          __builtin_amdgcn_s_sleep(1);
        }
      }
      // (poll drained vmcnt to 0 -- pipeline counts below are exact)

      // ---- A-frags straight from XCD L2, 12-deep pipeline, 32 MFMAs ----
      const u16* abase;
      if (LAYER == 0) abase = x1 + ((size_t)tprev * 64 + am) * 1024 + dir * 512;
      else            abase = hexch + ((size_t)tprev * 2 + dir) * (64 * 512) + (size_t)am * 512;

      short8 hv[32];
      #pragma unroll
      for (int p = 0; p < 12; ++p){
        const u16* src = abase + p * 16 + cb8;
        asm volatile("global_load_dwordx4 %0, %1, off sc0" : "=v"(hv[p]) : "v"(src));
      }
      f32x16 a1 = {0,0,0,0,0,0,0,0,0,0,0,0,0,0,0,0};
      f32x16 a2 = {0,0,0,0,0,0,0,0,0,0,0,0,0,0,0,0};
      #pragma unroll
      for (int g = 0; g < 8; ++g){
        if (g < 5){
          #pragma unroll
          for (int p = 0; p < 4; ++p){
            int q = (g + 3) * 4 + p;
            const u16* src = abase + q * 16 + cb8;
            asm volatile("global_load_dwordx4 %0, %1, off sc0" : "=v"(hv[q]) : "v"(src));
          }
          asm volatile("s_waitcnt vmcnt(12)" ::: "memory");
        } else if (g == 5){
          asm volatile("s_waitcnt vmcnt(8)" ::: "memory");
        } else if (g == 6){
          asm volatile("s_waitcnt vmcnt(4)" ::: "memory");
        } else {
          asm volatile("s_waitcnt vmcnt(0)" ::: "memory");
        }
        __builtin_amdgcn_sched_barrier(0);
        #pragma unroll
        for (int p = 0; p < 4; ++p){
          int kk = g * 4 + p;
          if (kk & 1) a2 = __builtin_amdgcn_mfma_f32_32x32x16_bf16(hv[kk], bq[kk], a2, 0, 0, 0);
          else        a1 = __builtin_amdgcn_mfma_f32_32x32x16_bf16(hv[kk], bq[kk], a1, 0, 0, 0);
        }
      }
      #pragma unroll
      for (int r = 0; r < 16; ++r) accv[r] = a1[r] + a2[r];
    }

    // gates to LDS: D[m][n]: n = lane&31(+wn), m = (r&3)+8*(r>>2)+4*(lane>>5) (+wm)
    #pragma unroll
    for (int r = 0; r < 16; ++r){
      int ml = wm + (r & 3) + 8 * (r >> 2) + 4 * (lane >> 5);
      gates_lds[g_of_n][ml][j_of_n] = accv[r];
    }
    __syncthreads();                 // #1: all waves' gate writes visible

    // gate math + state update
    short4v hout;
    float hof[4];
    #pragma unroll
    for (int q = 0; q < 4; ++q){
      const int j = gj + q;
      float gi = gates_lds[0][gm][j] + bf2f(xgv[0][q]);
      float gf = gates_lds[1][gm][j] + bf2f(xgv[1][q]);
      float gg = gates_lds[2][gm][j] + bf2f(xgv[2][q]);
      float go = gates_lds[3][gm][j] + bf2f(xgv[3][q]);
      float iv = sigm(gi), fv = sigm(gf), gv = tanhx(gg), ov = sigm(go);
      float c  = fv * cst[q] + iv * gv;
      cst[q]   = c;
      float h  = ov * tanhx(c);
      hof[q]   = h;
      hout[q]  = (short)f2bf(h);
    }

    // publish h via XCD-local L2 stores (fresh addresses every step)
    if (LAYER == 0){
      u16* dst = x1 + ((size_t)t * 64 + gm) * 1024 + dir * 512 + s * 16 + gj;
      st8_l2(dst, hout);
    } else {
      float4 dv = { hof[0], hof[1], hof[2], hof[3] };
      *(float4*)(dout + ((size_t)gm * 512 + t) * 1024 + dir * 512 + s * 16 + gj) = dv;
      u16* dst = hexch + ((size_t)t * 2 + dir) * (64 * 512) + gm * 512 + s * 16 + gj;
      st8_l2(dst, hout);
    }

    asm volatile("s_waitcnt vmcnt(0)" ::: "memory");   // h stores ack'd in L2
    __syncthreads();                 // #2: all waves drained; gates_lds reusable
    if (tid == 0) st4_ag(flgd + s, it + 1);            // publish (agent scope)
  }
}

extern "C" void kernel_launch(void* const* d_in, const int* in_sizes, int n_in,
                              void* d_out, int out_size, void* d_ws, size_t ws_size,
                              hipStream_t stream){
  (void)in_sizes; (void)n_in; (void)out_size; (void)ws_size;
  const float* seq = (const float*)d_in[0];
  const float* wih = (const float*)d_in[2];
  const float* whh = (const float*)d_in[3];
  const float* bih = (const float*)d_in[4];
  const float* bhh = (const float*)d_in[5];
  float* out = (float*)d_out;

  // control block (8 KB): per-layer election ctrl (256 ints each) + flags (128 ints each)
  char* ws    = (char*)d_ws;
  int*  ctrl0 = (int*)ws;            // ints [0..255]
  int*  ctrl1 = ctrl0 + 256;         // ints [256..511]
  int*  flg0  = ctrl0 + 512;         // ints [512..639]
  int*  flg1  = ctrl0 + 640;         // ints [640..767]

  u16*  seqb = (u16*)(ws + 8192);                       // 33,554,432 u16 (64 MB)
  u16*  wihb = seqb + (size_t)33554432;                 //  8,388,608
  u16*  whhb = wihb + (size_t)8388608;                  //  4,194,304
  u16*  x1   = whhb + (size_t)4194304;                  // 33,554,432
  u16*  xgb  = x1   + (size_t)33554432;                 // 134,217,728
  u16*  hexb = seqb;   // layer1 t-indexed h exchange [512][2][64][512] aliases seqb
                       // (seqb is dead after k_gemm<1>, sizes match: 64 MB)

  hipMemsetAsync(ctrl0, 0, 8192, stream);
  k_cvt<<<32768, 256, 0, stream>>>(seq, seqb, 8388608);
  k_cvt<<<8192,  256, 0, stream>>>(wih, wihb, 2097152);
  k_cvt<<<4096,  256, 0, stream>>>(whh, whhb, 1048576);

  dim3 gg(256, 32);
  // layer 0
  k_gemm<1><<<gg, 256, 0, stream>>>(seqb, wihb, bih, bhh, xgb);
  k_rec<0><<<512, 256, 0, stream>>>(whhb, xgb, x1, hexb, out, ctrl0, flg0);
  // layer 1
  k_gemm<0><<<gg, 256, 0, stream>>>(x1, wihb + 4194304, bih + 4096, bhh + 4096, xgb);
  k_rec<1><<<512, 256, 0, stream>>>(whhb + 2097152, xgb, x1, hexb, out, ctrl1, flg1);
}

// Round 6
// 5230.104 us; speedup vs baseline: 1.3866x; 1.3866x over previous
//
#include <hip/hip_runtime.h>
#include <cstdint>

typedef unsigned short u16;
typedef __attribute__((ext_vector_type(8))) short short8;     // 8 x bf16 (4 VGPRs)
typedef __attribute__((ext_vector_type(4))) short short4v;    // 4 x bf16 (2 VGPRs)
typedef __attribute__((ext_vector_type(4))) float f32x4;
typedef __attribute__((ext_vector_type(16))) float f32x16;

// B=64, T=512, H=512, D_IN=1024, L=2, DIRS=2
// xg matrix: M = T*B = 32768 rows (m = t*64 + b), N = 4096 cols (n = dir*2048 + gate*512 + j)

__device__ __forceinline__ u16 f2bf(float x){
  uint32_t u = __float_as_uint(x);
  u += 0x7fffu + ((u >> 16) & 1u);          // RNE
  return (u16)(u >> 16);
}
__device__ __forceinline__ float bf2f(u16 b){ return __uint_as_float(((uint32_t)b) << 16); }
__device__ __forceinline__ float sigm(float x){ return 1.f / (1.f + __expf(-x)); }
__device__ __forceinline__ float tanhx(float x){
  float xc = fminf(fmaxf(x, -30.f), 30.f);
  float e  = __expf(-2.f * xc);
  return (1.f - e) / (1.f + e);
}

// XCD-local data ops (write-once/read-once addresses ONLY -- L2-served).
__device__ __forceinline__ void st8_l2(u16* p, short4v v){
  asm volatile("global_store_dwordx2 %0, %1, off sc0" :: "v"(p), "v"(v) : "memory");
}
// agent-scope flag store (coherent point). Spin-polled addresses MUST use sc1:
// round-4 evidence: sc0-only flag store/poll deadlocks (stale line re-read forever).
__device__ __forceinline__ void st4_ag(int* p, int v){
  asm volatile("global_store_dword %0, %1, off sc1" :: "v"(p), "v"(v) : "memory");
}

#define FLG_STRIDE 32   // ints: one 128B line per producer flag (hot-line fix, round 6)

// ---------------- fp32 -> bf16 convert ----------------
__global__ void k_cvt(const float* __restrict__ in, u16* __restrict__ out, int n4){
  int i = blockIdx.x * blockDim.x + threadIdx.x;
  if (i >= n4) return;
  float4 v = ((const float4*)in)[i];
  ushort4 o;
  o.x = f2bf(v.x); o.y = f2bf(v.y); o.z = f2bf(v.z); o.w = f2bf(v.w);
  ((ushort4*)out)[i] = o;
}

// ---------------- input GEMM: xg = A @ W^T + bias, bf16 in, bf16 out ----------------
template<int LAYER0>
__global__ __launch_bounds__(256) void k_gemm(
    const u16* __restrict__ A, const u16* __restrict__ W,
    const float* __restrict__ bih, const float* __restrict__ bhh,
    u16* __restrict__ xg)
{
  __shared__ u16 Al[128 * 64];
  __shared__ u16 Bl[128 * 64];
  const int tid  = threadIdx.x;
  const int bm   = blockIdx.x, bn = blockIdx.y;
  const int w    = tid >> 6, lane = tid & 63;
  const int wm   = (w >> 1) * 64;
  const int wn   = (w & 1) * 64;
  f32x4 acc[4][4] = {};

  for (int kt = 0; kt < 1024; kt += 64){
    __syncthreads();
    #pragma unroll
    for (int it = 0; it < 4; ++it){
      int idx = tid + it * 256;
      int row = idx >> 3, c = idx & 7;
      size_t aoff;
      int m = bm * 128 + row;
      if (LAYER0) aoff = ((size_t)(m & 63) * 512 + (m >> 6)) * 1024;
      else        aoff = (size_t)m * 1024;
      short8 va = *(const short8*)(A + aoff + kt + c * 8);
      *(short8*)(Al + row * 64 + ((c ^ (row & 7)) * 8)) = va;
      int n = bn * 128 + row;
      short8 vb = *(const short8*)(W + (size_t)n * 1024 + kt + c * 8);
      *(short8*)(Bl + row * 64 + ((c ^ (row & 7)) * 8)) = vb;
    }
    __syncthreads();
    const int kg = lane >> 4;
    #pragma unroll
    for (int kk = 0; kk < 2; ++kk){
      short8 a[4], b[4];
      #pragma unroll
      for (int i = 0; i < 4; ++i){
        int rA = wm + i * 16 + (lane & 15);
        int cA = kk * 4 + kg;
        a[i] = *(const short8*)(Al + rA * 64 + ((cA ^ (rA & 7)) * 8));
        int rB = wn + i * 16 + (lane & 15);
        b[i] = *(const short8*)(Bl + rB * 64 + ((cA ^ (rB & 7)) * 8));
      }
      #pragma unroll
      for (int i = 0; i < 4; ++i)
        #pragma unroll
        for (int j = 0; j < 4; ++j)
          acc[i][j] = __builtin_amdgcn_mfma_f32_16x16x32_bf16(a[i], b[j], acc[i][j], 0, 0, 0);
    }
  }
  #pragma unroll
  for (int i = 0; i < 4; ++i){
    #pragma unroll
    for (int j = 0; j < 4; ++j){
      int n_g = bn * 128 + wn + j * 16 + (lane & 15);
      float bias = bih[n_g] + bhh[n_g];
      #pragma unroll
      for (int q = 0; q < 4; ++q){
        int m_g = bm * 128 + wm + i * 16 + (lane >> 4) * 4 + q;
        xg[(size_t)m_g * 4096 + n_g] = f2bf(acc[i][j][q] + bias);
      }
    }
  }
}

// ---------------- persistent LSTM recurrence, XCD-local exchange ----------------
// Election (round-3 proven): first 32 WGs per XCD are workers; first XCD claims dir0,
// second dir1; others exit. One dir == one XCD => h exchange stays in XCD-local L2.
// Round-6: per-producer flags PADDED to one 128B line each (hot-line fix). Structure
// otherwise identical to round 3 (LDS staging of h, w0 poll, gates_lds exchange).
template<int LAYER>
__global__ __launch_bounds__(256, 1) void k_rec(
    const u16* __restrict__ whh,   // (2, 2048, 512) bf16, this layer
    const u16* __restrict__ xg,    // (32768, 4096) bf16
    u16*  __restrict__ x1,         // (32768, 1024) bf16: layer0 output + layer0 h exchange
    u16*  __restrict__ hexch,      // [512 t][2 dir][64][512] bf16: layer1 h exchange
    float* __restrict__ dout,      // (64, 512, 1024) fp32 final output
    int*  __restrict__ ctrl,       // election block: cnt[8*16], dirmap@128..135, ndirs@136
    int*  __restrict__ flg)        // flags: [dir][32 producers], 128B-padded per producer
{
  const int tid = threadIdx.x;
  __shared__ int sh_rank, sh_dir;

  if (tid == 0){
    uint32_t xcd;
    asm volatile("s_getreg_b32 %0, hwreg(HW_REG_XCC_ID)" : "=s"(xcd));
    xcd &= 7;
    int rank = __hip_atomic_fetch_add(ctrl + xcd * 16, 1, __ATOMIC_RELAXED, __HIP_MEMORY_SCOPE_AGENT);
    int dm;
    if (rank == 0){
      int slot = __hip_atomic_fetch_add(ctrl + 136, 1, __ATOMIC_RELAXED, __HIP_MEMORY_SCOPE_AGENT);
      dm = slot + 1;
      __hip_atomic_store(ctrl + 128 + xcd, dm, __ATOMIC_RELEASE, __HIP_MEMORY_SCOPE_AGENT);
    } else {
      do {
        dm = __hip_atomic_load(ctrl + 128 + xcd, __ATOMIC_ACQUIRE, __HIP_MEMORY_SCOPE_AGENT);
      } while (dm == 0);
    }
    sh_rank = rank; sh_dir = dm - 1;
  }
  __syncthreads();
  const int s   = sh_rank;
  const int dir = sh_dir;
  if (s >= 32 || dir >= 2) return;     // not a worker

  const int w    = tid >> 6, lane = tid & 63;
  const int wm   = (w >> 1) * 32;      // batch-row offset of this wave
  const int wn   = (w & 1) * 32;       // col offset within WG's 64 cols

  __shared__ u16  h_lds[64 * 512];     // 64 KB, 16B-chunk XOR swizzled
  __shared__ float gates_lds[4][64][16];

  // W^T slice into registers: B-frag[kk]: B[k][n], n = wn+(lane&31)
  const u16* wd = whh + (size_t)dir * (2048 * 512);
  const int  nl = wn + (lane & 31);
  const int  g_of_n = nl >> 4, j_of_n = nl & 15;
  short8 bq[32];
  {
    const size_t rbase = (size_t)(g_of_n * 512 + s * 16 + j_of_n) * 512;
    const int ko = (lane >> 5) * 8;
    #pragma unroll
    for (int kk = 0; kk < 32; ++kk)
      bq[kk] = *(const short8*)(wd + rbase + kk * 16 + ko);
  }

  float cst[4] = {0.f, 0.f, 0.f, 0.f};
  const int tstep = dir ? -1 : 1;
  const int t0    = dir ? 511 : 0;
  int* const flgd = flg + dir * 32 * FLG_STRIDE;

  // gate-math geometry: thread owns batch gm, cols gj..gj+3
  const int gm = tid >> 2;
  const int gj = 4 * (tid & 3);

  for (int it = 0; it < 512; ++it){
    const int t = t0 + tstep * it;

    // prefetch this step's xg gate values (plain cached loads; hide under poll)
    const size_t xb0 = ((size_t)t * 64 + gm) * 4096 + (size_t)dir * 2048 + s * 16 + gj;
    ushort4 xgv[4];
    #pragma unroll
    for (int g = 0; g < 4; ++g) xgv[g] = *(const ushort4*)(xg + xb0 + g * 512);

    float accv[16];
    #pragma unroll
    for (int r = 0; r < 16; ++r) accv[r] = 0.f;

    if (it > 0){
      const int tprev = t - tstep;
      // ---- wait for all 32 producers of this dir (sc1 poll, one line per flag) ----
      if (w == 0){
        const int* fp = flgd + (lane & 31) * FLG_STRIDE;
        while (true){
          int v;
          asm volatile("global_load_dword %0, %1, off sc1\n\ts_waitcnt vmcnt(0)"
                       : "=v"(v) : "v"(fp) : "memory");
          if (__all(v >= it)) break;
          __builtin_amdgcn_s_sleep(1);
        }
      }
      __syncthreads();

      // ---- stage h(t-1) (64 x 512 bf16 = 64KB) into LDS via XCD-local L2 loads ----
      const u16* hsrc;
      size_t rstride;
      if (LAYER == 0){ hsrc = x1 + ((size_t)tprev * 64) * 1024 + dir * 512; rstride = 1024; }
      else           { hsrc = hexch + ((size_t)tprev * 2 + dir) * (64 * 512); rstride = 512; }

      short8 hv[16];
      #pragma unroll
      for (int i = 0; i < 16; ++i){
        int idx = i * 256 + tid;
        int row = idx >> 6, c = idx & 63;
        const u16* src = hsrc + (size_t)row * rstride + c * 8;
        asm volatile("global_load_dwordx4 %0, %1, off sc0" : "=v"(hv[i]) : "v"(src));
      }
      asm volatile("s_waitcnt vmcnt(8)" ::: "memory");
      __builtin_amdgcn_sched_barrier(0);
      #pragma unroll
      for (int i = 0; i < 8; ++i){
        int idx = i * 256 + tid;
        int row = idx >> 6, c = idx & 63;
        *(short8*)(h_lds + row * 512 + ((c ^ (row & 7)) * 8)) = hv[i];
      }
      asm volatile("s_waitcnt vmcnt(0)" ::: "memory");
      __builtin_amdgcn_sched_barrier(0);
      #pragma unroll
      for (int i = 8; i < 16; ++i){
        int idx = i * 256 + tid;
        int row = idx >> 6, c = idx & 63;
        *(short8*)(h_lds + row * 512 + ((c ^ (row & 7)) * 8)) = hv[i];
      }
      __syncthreads();

      // ---- MFMA: acc[m][n] = sum_k h[m][k] * W^T[k][n] ----
      f32x16 a1 = {0,0,0,0,0,0,0,0,0,0,0,0,0,0,0,0};
      f32x16 a2 = {0,0,0,0,0,0,0,0,0,0,0,0,0,0,0,0};
      const int m  = wm + (lane & 31);
      const int cb = (lane >> 5);
      #pragma unroll
      for (int kk = 0; kk < 32; ++kk){
        int c = kk * 2 + cb;
        short8 a = *(const short8*)(h_lds + m * 512 + ((c ^ (m & 7)) * 8));
        if (kk & 1) a2 = __builtin_amdgcn_mfma_f32_32x32x16_bf16(a, bq[kk], a2, 0, 0, 0);
        else        a1 = __builtin_amdgcn_mfma_f32_32x32x16_bf16(a, bq[kk], a1, 0, 0, 0);
      }
      #pragma unroll
      for (int r = 0; r < 16; ++r) accv[r] = a1[r] + a2[r];
    }

    // gates to LDS: D[m][n]: n = lane&31(+wn), m = (r&3)+8*(r>>2)+4*(lane>>5) (+wm)
    #pragma unroll
    for (int r = 0; r < 16; ++r){
      int ml = wm + (r & 3) + 8 * (r >> 2) + 4 * (lane >> 5);
      gates_lds[g_of_n][ml][j_of_n] = accv[r];
    }
    __syncthreads();

    // gate math + state update
    short4v hout;
    float hof[4];
    #pragma unroll
    for (int q = 0; q < 4; ++q){
      const int j = gj + q;
      float gi = gates_lds[0][gm][j] + bf2f(xgv[0][q]);
      float gf = gates_lds[1][gm][j] + bf2f(xgv[1][q]);
      float gg = gates_lds[2][gm][j] + bf2f(xgv[2][q]);
      float go = gates_lds[3][gm][j] + bf2f(xgv[3][q]);
      float iv = sigm(gi), fv = sigm(gf), gv = tanhx(gg), ov = sigm(go);
      float c  = fv * cst[q] + iv * gv;
      cst[q]   = c;
      float h  = ov * tanhx(c);
      hof[q]   = h;
      hout[q]  = (short)f2bf(h);
    }

    // publish h via XCD-local L2 stores (fresh addresses every step).
    // Layer 1: hexch FIRST, then dout; wait vmcnt(1) -- oldest (hexch) must be done,
    // the HBM dout store may still be in flight (write-only, never read back).
    if (LAYER == 0){
      u16* dst = x1 + ((size_t)t * 64 + gm) * 1024 + dir * 512 + s * 16 + gj;
      st8_l2(dst, hout);
      asm volatile("s_waitcnt vmcnt(0)" ::: "memory");
    } else {
      u16* dst = hexch + ((size_t)t * 2 + dir) * (64 * 512) + gm * 512 + s * 16 + gj;
      st8_l2(dst, hout);
      float4 dv = { hof[0], hof[1], hof[2], hof[3] };
      *(float4*)(dout + ((size_t)gm * 512 + t) * 1024 + dir * 512 + s * 16 + gj) = dv;
      asm volatile("s_waitcnt vmcnt(1)" ::: "memory");
    }
    __syncthreads();                                   // all threads' h stores done
    if (tid == 0) st4_ag(flgd + s * FLG_STRIDE, it + 1);  // publish (agent scope, own line)
  }
}

extern "C" void kernel_launch(void* const* d_in, const int* in_sizes, int n_in,
                              void* d_out, int out_size, void* d_ws, size_t ws_size,
                              hipStream_t stream){
  (void)in_sizes; (void)n_in; (void)out_size; (void)ws_size;
  const float* seq = (const float*)d_in[0];
  const float* wih = (const float*)d_in[2];
  const float* whh = (const float*)d_in[3];
  const float* bih = (const float*)d_in[4];
  const float* bhh = (const float*)d_in[5];
  float* out = (float*)d_out;

  // control block: per-layer election ctrl (256 ints each) + padded flags
  // flg: per layer 2 dirs x 32 producers x 32 ints (128B/flag) = 2048 ints = 8KB
  char* ws    = (char*)d_ws;
  int*  ctrl0 = (int*)ws;            // ints [0..255]
  int*  ctrl1 = ctrl0 + 256;         // ints [256..511]
  int*  flg0  = ctrl0 + 512;         // ints [512..2559]
  int*  flg1  = ctrl0 + 2560;        // ints [2560..4607]

  u16*  seqb = (u16*)(ws + 32768);                      // 33,554,432 u16 (64 MB)
  u16*  wihb = seqb + (size_t)33554432;                 //  8,388,608
  u16*  whhb = wihb + (size_t)8388608;                  //  4,194,304
  u16*  x1   = whhb + (size_t)4194304;                  // 33,554,432
  u16*  xgb  = x1   + (size_t)33554432;                 // 134,217,728
  u16*  hexb = seqb;   // layer1 t-indexed h exchange [512][2][64][512] aliases seqb
                       // (seqb is dead after k_gemm<1>, sizes match: 64 MB)

  hipMemsetAsync(ctrl0, 0, 32768, stream);
  k_cvt<<<32768, 256, 0, stream>>>(seq, seqb, 8388608);
  k_cvt<<<8192,  256, 0, stream>>>(wih, wihb, 2097152);
  k_cvt<<<4096,  256, 0, stream>>>(whh, whhb, 1048576);

  dim3 gg(256, 32);
  // layer 0
  k_gemm<1><<<gg, 256, 0, stream>>>(seqb, wihb, bih, bhh, xgb);
  k_rec<0><<<512, 256, 0, stream>>>(whhb, xgb, x1, hexb, out, ctrl0, flg0);
  // layer 1
  k_gemm<0><<<gg, 256, 0, stream>>>(x1, wihb + 4194304, bih + 4096, bhh + 4096, xgb);
  k_rec<1><<<512, 256, 0, stream>>>(whhb + 2097152, xgb, x1, hexb, out, ctrl1, flg1);
}